// Round 5
// baseline (23.705 us; speedup 1.0000x reference)
//
#include <hip/hip_runtime.h>

// CenterLoss: mean_i clip(||x_i - c_{labels[i]}||^2, 1e-12, 1e12)
// N=8192, D=128, M=32000.
// Two graph nodes: 4-byte memset(out=0) + one kernel where each block
// atomicAdds its partial/N into out. Block atomics arrive staggered ->
// ~0.5us tail, cheaper than a second reduce dispatch (~1.5us).
// FP-atomic ordering noise ~1e-4 on a ~256-magnitude loss (threshold 5.12).

#define N_ROWS 8192
#define DIM    128
#define NBLK   1024     // 1024 blocks * 4 waves * 2 rows/wave = 8192 rows
#define NTHR   256

__global__ __launch_bounds__(NTHR) void centerloss_atomic(
        const float* __restrict__ x,
        const float* __restrict__ c,
        const int*   __restrict__ labels,
        float* __restrict__ out) {
    const int lane = threadIdx.x & 63;
    const int wid  = threadIdx.x >> 6;            // wave in block (0..3)
    const int wave = blockIdx.x * 4 + wid;        // 0..4095
    const int half = lane >> 5;                   // which of the wave's 2 rows
    const int l32  = lane & 31;                   // lane within 32-lane row group
    const int row  = wave * 2 + half;

    const int lbl = labels[row];
    const float4 xv = *reinterpret_cast<const float4*>(x + (size_t)row * DIM + l32 * 4);
    const float4 cv = *reinterpret_cast<const float4*>(c + (size_t)lbl * DIM + l32 * 4);
    const float d0 = xv.x - cv.x;
    const float d1 = xv.y - cv.y;
    const float d2 = xv.z - cv.z;
    const float d3 = xv.w - cv.w;
    float s = d0 * d0 + d1 * d1 + d2 * d2 + d3 * d3;

    // reduce each 32-lane half (one row each)
    #pragma unroll
    for (int off = 16; off > 0; off >>= 1)
        s += __shfl_down(s, off, 32);
    s = fminf(fmaxf(s, 1e-12f), 1e12f);           // clip
    const float sB = __shfl(s, 32, 64);           // row-B clipped sum

    __shared__ float lds[4];
    if (lane == 0) lds[wid] = s + sB;
    __syncthreads();
    if (threadIdx.x == 0) {
        const float p = lds[0] + lds[1] + lds[2] + lds[3];
        atomicAdd(out, p * (1.0f / (float)N_ROWS));   // device-scope by default
    }
}

extern "C" void kernel_launch(void* const* d_in, const int* in_sizes, int n_in,
                              void* d_out, int out_size, void* d_ws, size_t ws_size,
                              hipStream_t stream) {
    const float* x      = (const float*)d_in[0];   // [8192, 128] fp32
    const float* center = (const float*)d_in[1];   // [32000, 128] fp32
    const int*   labels = (const int*)d_in[2];     // [8192] int
    float* out = (float*)d_out;

    hipMemsetAsync(out, 0, sizeof(float), stream);  // graph-capturable memset node
    centerloss_atomic<<<NBLK, NTHR, 0, stream>>>(x, center, labels, out);
}